// Round 1
// baseline (943.310 us; speedup 1.0000x reference)
//
#include <hip/hip_runtime.h>
#include <stdint.h>

#define NCH 12
#define DS 160
#define HS 160
#define WS 160
#define HW (HS * WS)
#define DHW (DS * HS * WS)   // 4,096,000 voxels

#define BSH 3                // bucket = 8x8x8 cells
#define NBUCKET 32768        // 15-bit morton key space (20 buckets/axis < 32)

// Channel-last bf16 grid: cell = 12 bf16 = 24 B = 6 uint32 (each uint packs
// channels {2k, 2k+1}, low half = even channel).

__device__ __forceinline__ uint32_t bf16_rne(float f) {
    uint32_t b = __float_as_uint(f);
    return (b + 0x7fffu + ((b >> 16) & 1u)) >> 16;
}

__device__ __forceinline__ uint32_t spread3(uint32_t v) {
    v &= 0x3FFu;
    v = (v | (v << 16)) & 0x030000FFu;
    v = (v | (v << 8))  & 0x0300F00Fu;
    v = (v | (v << 4))  & 0x030C30C3u;
    v = (v | (v << 2))  & 0x09249249u;
    return v;
}

// Shared coordinate transform: MUST be identical in hist/scatter (same exact
// float ops -> same key both passes).
__device__ __forceinline__ void to_grid(float p0, float p1, float p2,
                                        const float* __restrict__ mn,
                                        const float* __restrict__ mx,
                                        float& px, float& py, float& pz) {
    float u0 = (p0 - mn[0]) / (mx[0] - mn[0]);
    float u1 = (p1 - mn[1]) / (mx[1] - mn[1]);
    float u2 = (p2 - mn[2]) / (mx[2] - mn[2]);
    px = u2 * (float)(WS - 1);   // col 2 -> W
    py = u1 * (float)(HS - 1);   // col 1 -> H
    pz = u0 * (float)(DS - 1);   // col 0 -> D
}

__device__ __forceinline__ uint32_t cell_key(float px, float py, float pz) {
    int x0 = min(max((int)floorf(px), 0), WS - 1);
    int y0 = min(max((int)floorf(py), 0), HS - 1);
    int z0 = min(max((int)floorf(pz), 0), DS - 1);
    return spread3((uint32_t)(x0 >> BSH))
         | (spread3((uint32_t)(y0 >> BSH)) << 1)
         | (spread3((uint32_t)(z0 >> BSH)) << 2);
}

// ---------------------------------------------------------------------------
// Kernel 1: transpose+convert [C, D*H*W] fp32 -> [D*H*W, 12] bf16.
// ---------------------------------------------------------------------------
__global__ __launch_bounds__(256) void transpose_bf16_kernel(
    const float* __restrict__ g, uint32_t* __restrict__ gt)
{
    int t = blockIdx.x * blockDim.x + threadIdx.x;   // handles voxels 4t..4t+3
    if (t >= DHW / 4) return;

    float vv[NCH][4];
#pragma unroll
    for (int c = 0; c < NCH; ++c) {
        float4 r = *(const float4*)(g + (size_t)c * DHW + 4 * (size_t)t);
        vv[c][0] = r.x; vv[c][1] = r.y; vv[c][2] = r.z; vv[c][3] = r.w;
    }

    uint32_t o[24];
#pragma unroll
    for (int j = 0; j < 4; ++j) {
#pragma unroll
        for (int k = 0; k < 6; ++k) {
            o[j * 6 + k] = bf16_rne(vv[2 * k][j]) | (bf16_rne(vv[2 * k + 1][j]) << 16);
        }
    }

    uint4* dst = (uint4*)(gt + (size_t)t * 24);      // 96 B, 16-aligned
#pragma unroll
    for (int q = 0; q < 6; ++q)
        dst[q] = make_uint4(o[4 * q], o[4 * q + 1], o[4 * q + 2], o[4 * q + 3]);
}

// ---------------------------------------------------------------------------
// Sort pipeline: zero -> histogram -> scan -> scatter
// ---------------------------------------------------------------------------
__global__ __launch_bounds__(256) void zero_u32_kernel(uint32_t* __restrict__ p, int n) {
    int i = blockIdx.x * blockDim.x + threadIdx.x;
    if (i < n) p[i] = 0u;
}

__global__ __launch_bounds__(256) void hist_kernel(
    const float* __restrict__ xyz, const float* __restrict__ mn,
    const float* __restrict__ mx, uint32_t* __restrict__ hist, int n)
{
    int t = blockIdx.x * blockDim.x + threadIdx.x;
    int i0 = 4 * t;
    if (i0 >= n) return;
    float p[4][3];
    int cnt;
    if (i0 + 4 <= n) {
        const float4* x4 = (const float4*)(xyz + 12 * (size_t)t);
        float4 a = x4[0], b = x4[1], c = x4[2];
        p[0][0]=a.x; p[0][1]=a.y; p[0][2]=a.z;
        p[1][0]=a.w; p[1][1]=b.x; p[1][2]=b.y;
        p[2][0]=b.z; p[2][1]=b.w; p[2][2]=c.x;
        p[3][0]=c.y; p[3][1]=c.z; p[3][2]=c.w;
        cnt = 4;
    } else {
        cnt = n - i0;
        for (int j = 0; j < cnt; ++j) {
            p[j][0]=xyz[3*(size_t)(i0+j)+0];
            p[j][1]=xyz[3*(size_t)(i0+j)+1];
            p[j][2]=xyz[3*(size_t)(i0+j)+2];
        }
    }
    for (int j = 0; j < cnt; ++j) {
        float px, py, pz;
        to_grid(p[j][0], p[j][1], p[j][2], mn, mx, px, py, pz);
        atomicAdd(&hist[cell_key(px, py, pz)], 1u);
    }
}

__global__ __launch_bounds__(1024) void scan_kernel(
    const uint32_t* __restrict__ hist, uint32_t* __restrict__ offs)
{
    __shared__ uint32_t part[1024];
    int t = threadIdx.x;
    uint32_t loc[32];
    uint32_t s = 0;
#pragma unroll
    for (int k = 0; k < 32; ++k) { loc[k] = hist[32 * t + k]; s += loc[k]; }
    part[t] = s;
    __syncthreads();
    for (int d = 1; d < 1024; d <<= 1) {
        uint32_t v = (t >= d) ? part[t - d] : 0u;
        __syncthreads();
        part[t] += v;
        __syncthreads();
    }
    uint32_t base = (t > 0) ? part[t - 1] : 0u;
#pragma unroll
    for (int k = 0; k < 32; ++k) { offs[32 * t + k] = base; base += loc[k]; }
}

__global__ __launch_bounds__(256) void scatter_kernel(
    const float* __restrict__ xyz, const float* __restrict__ mn,
    const float* __restrict__ mx, uint32_t* __restrict__ offs,
    float4* __restrict__ sorted, int n)
{
    int t = blockIdx.x * blockDim.x + threadIdx.x;
    int i0 = 4 * t;
    if (i0 >= n) return;
    float p[4][3];
    int cnt;
    if (i0 + 4 <= n) {
        const float4* x4 = (const float4*)(xyz + 12 * (size_t)t);
        float4 a = x4[0], b = x4[1], c = x4[2];
        p[0][0]=a.x; p[0][1]=a.y; p[0][2]=a.z;
        p[1][0]=a.w; p[1][1]=b.x; p[1][2]=b.y;
        p[2][0]=b.z; p[2][1]=b.w; p[2][2]=c.x;
        p[3][0]=c.y; p[3][1]=c.z; p[3][2]=c.w;
        cnt = 4;
    } else {
        cnt = n - i0;
        for (int j = 0; j < cnt; ++j) {
            p[j][0]=xyz[3*(size_t)(i0+j)+0];
            p[j][1]=xyz[3*(size_t)(i0+j)+1];
            p[j][2]=xyz[3*(size_t)(i0+j)+2];
        }
    }
    for (int j = 0; j < cnt; ++j) {
        float px, py, pz;
        to_grid(p[j][0], p[j][1], p[j][2], mn, mx, px, py, pz);
        uint32_t key = cell_key(px, py, pz);
        uint32_t pos = atomicAdd(&offs[key], 1u);
        // idx <= 2^21 fits exactly in fp32
        sorted[pos] = make_float4(px, py, pz, (float)(i0 + j));
    }
}

// ---------------------------------------------------------------------------
// Sample kernels
// ---------------------------------------------------------------------------
__device__ __forceinline__ void load_cell(const uint32_t* __restrict__ gt,
                                          int idx, uint32_t u[6]) {
    const uint2* p = (const uint2*)(gt + (size_t)idx * 6);  // 8-B aligned
    uint2 a = p[0], b = p[1], c = p[2];
    u[0] = a.x; u[1] = a.y; u[2] = b.x; u[3] = b.y; u[4] = c.x; u[5] = c.y;
}

__device__ __forceinline__ void acc_cell(const uint32_t u[6], float w,
                                         float acc[NCH]) {
#pragma unroll
    for (int k = 0; k < 6; ++k) {
        float lo = __uint_as_float(u[k] << 16);
        float hi = __uint_as_float(u[k] & 0xffff0000u);
        acc[2 * k]     = fmaf(w, lo, acc[2 * k]);
        acc[2 * k + 1] = fmaf(w, hi, acc[2 * k + 1]);
    }
}

__device__ __forceinline__ void trilinear_core(float px, float py, float pz,
                                               const uint32_t* __restrict__ gt,
                                               float acc[NCH]) {
    float x0f = floorf(px), y0f = floorf(py), z0f = floorf(pz);
    float fx = px - x0f, fy = py - y0f, fz = pz - z0f;

    int x0 = min(max((int)x0f, 0), WS - 1);
    int y0 = min(max((int)y0f, 0), HS - 1);
    int z0 = min(max((int)z0f, 0), DS - 1);
    int x1 = min(x0 + 1, WS - 1);
    int y1 = min(y0 + 1, HS - 1);
    int z1 = min(z0 + 1, DS - 1);

    float wx0 = 1.0f - fx, wx1 = fx;
    float wy0 = 1.0f - fy, wy1 = fy;
    float wz0 = 1.0f - fz, wz1 = fz;

    float w000 = wz0 * wy0 * wx0, w001 = wz0 * wy0 * wx1;
    float w010 = wz0 * wy1 * wx0, w011 = wz0 * wy1 * wx1;
    float w100 = wz1 * wy0 * wx0, w101 = wz1 * wy0 * wx1;
    float w110 = wz1 * wy1 * wx0, w111 = wz1 * wy1 * wx1;

    int zo0 = z0 * HW, zo1 = z1 * HW;
    int yo0 = y0 * WS, yo1 = y1 * WS;

#pragma unroll
    for (int c = 0; c < NCH; ++c) acc[c] = 0.0f;

    {
        uint32_t a[6], b[6];
        load_cell(gt, zo0 + yo0 + x0, a);
        load_cell(gt, zo0 + yo0 + x1, b);
        acc_cell(a, w000, acc);
        acc_cell(b, w001, acc);
    }
    {
        uint32_t a[6], b[6];
        load_cell(gt, zo0 + yo1 + x0, a);
        load_cell(gt, zo0 + yo1 + x1, b);
        acc_cell(a, w010, acc);
        acc_cell(b, w011, acc);
    }
    {
        uint32_t a[6], b[6];
        load_cell(gt, zo1 + yo0 + x0, a);
        load_cell(gt, zo1 + yo0 + x1, b);
        acc_cell(a, w100, acc);
        acc_cell(b, w101, acc);
    }
    {
        uint32_t a[6], b[6];
        load_cell(gt, zo1 + yo1 + x0, a);
        load_cell(gt, zo1 + yo1 + x1, b);
        acc_cell(a, w110, acc);
        acc_cell(b, w111, acc);
    }
}

// Sorted-points sampler: points arrive Morton-bucketed, grid-space coords +
// original index packed in float4.
__global__ __launch_bounds__(256) void sample_sorted_kernel(
    const float4* __restrict__ sorted,
    const uint32_t* __restrict__ gt,
    float* __restrict__ out, int n)
{
    int i = blockIdx.x * blockDim.x + threadIdx.x;
    if (i >= n) return;

    float4 s = sorted[i];
    int idx = (int)s.w;

    float acc[NCH];
    trilinear_core(s.x, s.y, s.z, gt, acc);

    float4* o4 = (float4*)(out + (size_t)idx * NCH);
    o4[0] = make_float4(acc[0], acc[1], acc[2], acc[3]);
    o4[1] = make_float4(acc[4], acc[5], acc[6], acc[7]);
    o4[2] = make_float4(acc[8], acc[9], acc[10], acc[11]);
}

// Unsorted fallback (previous best).
__global__ __launch_bounds__(256) void densegrid_sample_bf16_kernel(
    const float* __restrict__ xyz,
    const uint32_t* __restrict__ gt,
    const float* __restrict__ xyz_min,
    const float* __restrict__ xyz_max,
    float* __restrict__ out,
    int n)
{
    int i = blockIdx.x * blockDim.x + threadIdx.x;
    if (i >= n) return;

    float px, py, pz;
    to_grid(xyz[3 * i + 0], xyz[3 * i + 1], xyz[3 * i + 2],
            xyz_min, xyz_max, px, py, pz);

    float acc[NCH];
    trilinear_core(px, py, pz, gt, acc);

    float4* o4 = (float4*)(out + (size_t)i * NCH);
    o4[0] = make_float4(acc[0], acc[1], acc[2], acc[3]);
    o4[1] = make_float4(acc[4], acc[5], acc[6], acc[7]);
    o4[2] = make_float4(acc[8], acc[9], acc[10], acc[11]);
}

// ---------------------------------------------------------------------------
// fp32 channel-first fallback (if workspace too small for bf16 grid).
// ---------------------------------------------------------------------------
__global__ __launch_bounds__(256) void densegrid_sample_chfirst_kernel(
    const float* __restrict__ xyz,
    const float* __restrict__ grid,
    const float* __restrict__ xyz_min,
    const float* __restrict__ xyz_max,
    float* __restrict__ out,
    int n)
{
    int i = blockIdx.x * blockDim.x + threadIdx.x;
    if (i >= n) return;

    float px, py, pz;
    to_grid(xyz[3 * i + 0], xyz[3 * i + 1], xyz[3 * i + 2],
            xyz_min, xyz_max, px, py, pz);

    float x0f = floorf(px), y0f = floorf(py), z0f = floorf(pz);
    float fx = px - x0f, fy = py - y0f, fz = pz - z0f;

    int x0 = min(max((int)x0f, 0), WS - 1);
    int y0 = min(max((int)y0f, 0), HS - 1);
    int z0 = min(max((int)z0f, 0), DS - 1);
    int x1 = min(x0 + 1, WS - 1);
    int y1 = min(y0 + 1, HS - 1);
    int z1 = min(z0 + 1, DS - 1);

    float wx0 = 1.0f - fx, wx1 = fx;
    float wy0 = 1.0f - fy, wy1 = fy;
    float wz0 = 1.0f - fz, wz1 = fz;

    float w000 = wz0 * wy0 * wx0, w001 = wz0 * wy0 * wx1;
    float w010 = wz0 * wy1 * wx0, w011 = wz0 * wy1 * wx1;
    float w100 = wz1 * wy0 * wx0, w101 = wz1 * wy0 * wx1;
    float w110 = wz1 * wy1 * wx0, w111 = wz1 * wy1 * wx1;

    int o00 = z0 * HW + y0 * WS;
    int o01 = z0 * HW + y1 * WS;
    int o10 = z1 * HW + y0 * WS;
    int o11 = z1 * HW + y1 * WS;

    float res[NCH];
#pragma unroll
    for (int c = 0; c < NCH; ++c) {
        const float* g = grid + (size_t)c * DHW;
        float acc = g[o00 + x0] * w000;
        acc = fmaf(g[o00 + x1], w001, acc);
        acc = fmaf(g[o01 + x0], w010, acc);
        acc = fmaf(g[o01 + x1], w011, acc);
        acc = fmaf(g[o10 + x0], w100, acc);
        acc = fmaf(g[o10 + x1], w111 == w111 ? w101 : w101, acc);
        acc = fmaf(g[o11 + x0], w110, acc);
        acc = fmaf(g[o11 + x1], w111, acc);
        res[c] = acc;
    }
    float4* o4 = (float4*)(out + (size_t)i * NCH);
    o4[0] = make_float4(res[0], res[1], res[2], res[3]);
    o4[1] = make_float4(res[4], res[5], res[6], res[7]);
    o4[2] = make_float4(res[8], res[9], res[10], res[11]);
}

extern "C" void kernel_launch(void* const* d_in, const int* in_sizes, int n_in,
                              void* d_out, int out_size, void* d_ws, size_t ws_size,
                              hipStream_t stream) {
    const float* xyz     = (const float*)d_in[0];
    const float* grid    = (const float*)d_in[1];
    const float* xyz_min = (const float*)d_in[2];
    const float* xyz_max = (const float*)d_in[3];
    float* out = (float*)d_out;

    int n = in_sizes[0] / 3;
    int block = 256;
    int blocks = (n + block - 1) / block;

    size_t gt_bytes  = (size_t)DHW * NCH * 2;            // 98,304,000 B
    size_t hist_off  = gt_bytes;                         // 16-aligned
    size_t offs_off  = hist_off + (size_t)NBUCKET * 4;
    size_t sort_off  = offs_off + (size_t)NBUCKET * 4;   // still 16-aligned
    size_t need_sort = sort_off + (size_t)n * 16;        // ~132.1 MB

    if (ws_size >= need_sort) {
        uint32_t* gt     = (uint32_t*)d_ws;
        uint32_t* hist   = (uint32_t*)((char*)d_ws + hist_off);
        uint32_t* offs   = (uint32_t*)((char*)d_ws + offs_off);
        float4*   sorted = (float4*)((char*)d_ws + sort_off);

        int tthreads = DHW / 4;
        int tblocks  = (tthreads + block - 1) / block;   // 4000
        int n4       = (n + 3) / 4;
        int pblocks  = (n4 + block - 1) / block;         // 2048

        transpose_bf16_kernel<<<tblocks, block, 0, stream>>>(grid, gt);
        zero_u32_kernel<<<NBUCKET / block, block, 0, stream>>>(hist, NBUCKET);
        hist_kernel<<<pblocks, block, 0, stream>>>(xyz, xyz_min, xyz_max, hist, n);
        scan_kernel<<<1, 1024, 0, stream>>>(hist, offs);
        scatter_kernel<<<pblocks, block, 0, stream>>>(xyz, xyz_min, xyz_max,
                                                      offs, sorted, n);
        sample_sorted_kernel<<<blocks, block, 0, stream>>>(sorted, gt, out, n);
    } else if (ws_size >= gt_bytes) {
        uint32_t* gt = (uint32_t*)d_ws;
        int tthreads = DHW / 4;
        int tblocks  = (tthreads + block - 1) / block;
        transpose_bf16_kernel<<<tblocks, block, 0, stream>>>(grid, gt);
        densegrid_sample_bf16_kernel<<<blocks, block, 0, stream>>>(
            xyz, gt, xyz_min, xyz_max, out, n);
    } else {
        densegrid_sample_chfirst_kernel<<<blocks, block, 0, stream>>>(
            xyz, grid, xyz_min, xyz_max, out, n);
    }
}

// Round 2
// 583.095 us; speedup vs baseline: 1.6178x; 1.6178x over previous
//
#include <hip/hip_runtime.h>
#include <stdint.h>

#define NCH 12
#define DS 160
#define HS 160
#define WS 160
#define HW (HS * WS)
#define DHW (DS * HS * WS)   // 4,096,000 voxels

// Coarse buckets: 5x5x5 over the volume, each 32^3 cells = 786 KB bf16 region
// (L2-resident). key = (zb*5 + yb)*5 + xb in [0,125).
#define NB 125
#define PTS_PER_BLOCK 4096   // sort pass: points handled per block

// Channel-last bf16 grid: cell = 12 bf16 = 24 B = 6 uint32 (each uint packs
// channels {2k, 2k+1}, low half = even channel).

__device__ __forceinline__ uint32_t bf16_rne(float f) {
    uint32_t b = __float_as_uint(f);
    return (b + 0x7fffu + ((b >> 16) & 1u)) >> 16;
}

// Shared coordinate transform: identical float ops in hist/scatter so the key
// is deterministic across passes.
__device__ __forceinline__ void to_grid(float p0, float p1, float p2,
                                        const float* __restrict__ mn,
                                        const float* __restrict__ mx,
                                        float& px, float& py, float& pz) {
    float u0 = (p0 - mn[0]) / (mx[0] - mn[0]);
    float u1 = (p1 - mn[1]) / (mx[1] - mn[1]);
    float u2 = (p2 - mn[2]) / (mx[2] - mn[2]);
    px = u2 * (float)(WS - 1);   // col 2 -> W
    py = u1 * (float)(HS - 1);   // col 1 -> H
    pz = u0 * (float)(DS - 1);   // col 0 -> D
}

__device__ __forceinline__ int bucket_key(float px, float py, float pz) {
    int x0 = min(max((int)floorf(px), 0), WS - 1);
    int y0 = min(max((int)floorf(py), 0), HS - 1);
    int z0 = min(max((int)floorf(pz), 0), DS - 1);
    return ((z0 >> 5) * 5 + (y0 >> 5)) * 5 + (x0 >> 5);
}

// ---------------------------------------------------------------------------
// Kernel 1: transpose+convert [C, D*H*W] fp32 -> [D*H*W, 12] bf16.
// ---------------------------------------------------------------------------
__global__ __launch_bounds__(256) void transpose_bf16_kernel(
    const float* __restrict__ g, uint32_t* __restrict__ gt)
{
    int t = blockIdx.x * blockDim.x + threadIdx.x;   // handles voxels 4t..4t+3
    if (t >= DHW / 4) return;

    float vv[NCH][4];
#pragma unroll
    for (int c = 0; c < NCH; ++c) {
        float4 r = *(const float4*)(g + (size_t)c * DHW + 4 * (size_t)t);
        vv[c][0] = r.x; vv[c][1] = r.y; vv[c][2] = r.z; vv[c][3] = r.w;
    }

    uint32_t o[24];
#pragma unroll
    for (int j = 0; j < 4; ++j) {
#pragma unroll
        for (int k = 0; k < 6; ++k) {
            o[j * 6 + k] = bf16_rne(vv[2 * k][j]) | (bf16_rne(vv[2 * k + 1][j]) << 16);
        }
    }

    uint4* dst = (uint4*)(gt + (size_t)t * 24);      // 96 B, 16-aligned
#pragma unroll
    for (int q = 0; q < 6; ++q)
        dst[q] = make_uint4(o[4 * q], o[4 * q + 1], o[4 * q + 2], o[4 * q + 3]);
}

// ---------------------------------------------------------------------------
// Sort pipeline (atomic-light): zero -> blockhist -> scan -> scatter
// ---------------------------------------------------------------------------
__global__ __launch_bounds__(128) void zero_total_kernel(uint32_t* __restrict__ total) {
    int t = threadIdx.x;
    if (t < NB) total[t] = 0u;
}

// Load helper: 4 consecutive points via 3 coalesced float4 reads.
__device__ __forceinline__ int load_pts4(const float* __restrict__ xyz, int i0,
                                         int n, float p[4][3]) {
    if (i0 >= n) return 0;
    if (i0 + 4 <= n) {
        const float4* x4 = (const float4*)(xyz + 3 * (size_t)i0);
        float4 a = x4[0], b = x4[1], c = x4[2];
        p[0][0]=a.x; p[0][1]=a.y; p[0][2]=a.z;
        p[1][0]=a.w; p[1][1]=b.x; p[1][2]=b.y;
        p[2][0]=b.z; p[2][1]=b.w; p[2][2]=c.x;
        p[3][0]=c.y; p[3][1]=c.z; p[3][2]=c.w;
        return 4;
    }
    int cnt = n - i0;
    for (int j = 0; j < cnt; ++j) {
        p[j][0]=xyz[3*(size_t)(i0+j)+0];
        p[j][1]=xyz[3*(size_t)(i0+j)+1];
        p[j][2]=xyz[3*(size_t)(i0+j)+2];
    }
    return cnt;
}

// Per-block LDS histogram; one global atomicAdd per (block,bucket).
__global__ __launch_bounds__(256) void hist_kernel(
    const float* __restrict__ xyz, const float* __restrict__ mn,
    const float* __restrict__ mx, uint32_t* __restrict__ total, int n)
{
    __shared__ uint32_t h[NB];
    int tid = threadIdx.x;
    if (tid < NB) h[tid] = 0u;
    __syncthreads();

    int base = blockIdx.x * PTS_PER_BLOCK;
#pragma unroll
    for (int k = 0; k < 4; ++k) {
        int i0 = base + k * 1024 + tid * 4;
        float p[4][3];
        int cnt = load_pts4(xyz, i0, n, p);
        for (int j = 0; j < cnt; ++j) {
            float px, py, pz;
            to_grid(p[j][0], p[j][1], p[j][2], mn, mx, px, py, pz);
            atomicAdd(&h[bucket_key(px, py, pz)], 1u);
        }
    }
    __syncthreads();
    if (tid < NB && h[tid]) atomicAdd(&total[tid], h[tid]);
}

// Exclusive scan of 125 totals -> cursor (segment reservation counters).
__global__ __launch_bounds__(128) void scan_base_kernel(
    const uint32_t* __restrict__ total, uint32_t* __restrict__ cursor)
{
    __shared__ uint32_t s[NB + 1];
    int t = threadIdx.x;
    if (t < NB) s[t + 1] = total[t];
    if (t == 0) s[0] = 0u;
    __syncthreads();
    if (t == 0) {
        uint32_t run = 0;
        for (int b = 0; b < NB; ++b) { uint32_t c = s[b + 1]; s[b + 1] = run; run += c; }
        // s[b+1] now = exclusive prefix of bucket b
    }
    __syncthreads();
    if (t < NB) cursor[t] = s[t + 1];
}

// Scatter: per-block LDS hist -> reserve contiguous segment per bucket via one
// cursor atomicAdd -> rank via LDS atomics -> direct global writes (same-block
// same-bucket writes are adjacent -> L2 write-merge). Optionally emits inverse
// permutation inv[orig_idx] = sorted_pos (coalesced: idx window contiguous).
__global__ __launch_bounds__(256) void scatter_kernel(
    const float* __restrict__ xyz, const float* __restrict__ mn,
    const float* __restrict__ mx, uint32_t* __restrict__ cursor,
    float4* __restrict__ sorted, uint32_t* __restrict__ inv, int n)
{
    __shared__ uint32_t h[NB];
    __shared__ uint32_t seg[NB];
    __shared__ uint32_t lcur[NB];
    int tid = threadIdx.x;
    if (tid < NB) { h[tid] = 0u; lcur[tid] = 0u; }
    __syncthreads();

    int base = blockIdx.x * PTS_PER_BLOCK;

    // phase A: count
#pragma unroll
    for (int k = 0; k < 4; ++k) {
        int i0 = base + k * 1024 + tid * 4;
        float p[4][3];
        int cnt = load_pts4(xyz, i0, n, p);
        for (int j = 0; j < cnt; ++j) {
            float px, py, pz;
            to_grid(p[j][0], p[j][1], p[j][2], mn, mx, px, py, pz);
            atomicAdd(&h[bucket_key(px, py, pz)], 1u);
        }
    }
    __syncthreads();

    // phase B: reserve global segments (125 device atomics per block)
    if (tid < NB) {
        uint32_t c = h[tid];
        seg[tid] = c ? atomicAdd(&cursor[tid], c) : 0u;
    }
    __syncthreads();

    // phase C: rank + write (xyz re-read is L2-hot)
#pragma unroll
    for (int k = 0; k < 4; ++k) {
        int i0 = base + k * 1024 + tid * 4;
        float p[4][3];
        int cnt = load_pts4(xyz, i0, n, p);
        for (int j = 0; j < cnt; ++j) {
            float px, py, pz;
            to_grid(p[j][0], p[j][1], p[j][2], mn, mx, px, py, pz);
            int b = bucket_key(px, py, pz);
            uint32_t pos = seg[b] + atomicAdd(&lcur[b], 1u);
            sorted[pos] = make_float4(px, py, pz, __uint_as_float((uint32_t)(i0 + j)));
            if (inv) inv[i0 + j] = pos;
        }
    }
}

// ---------------------------------------------------------------------------
// Sample kernels
// ---------------------------------------------------------------------------
__device__ __forceinline__ void load_cell(const uint32_t* __restrict__ gt,
                                          int idx, uint32_t u[6]) {
    const uint2* p = (const uint2*)(gt + (size_t)idx * 6);  // 8-B aligned
    uint2 a = p[0], b = p[1], c = p[2];
    u[0] = a.x; u[1] = a.y; u[2] = b.x; u[3] = b.y; u[4] = c.x; u[5] = c.y;
}

__device__ __forceinline__ void acc_cell(const uint32_t u[6], float w,
                                         float acc[NCH]) {
#pragma unroll
    for (int k = 0; k < 6; ++k) {
        float lo = __uint_as_float(u[k] << 16);
        float hi = __uint_as_float(u[k] & 0xffff0000u);
        acc[2 * k]     = fmaf(w, lo, acc[2 * k]);
        acc[2 * k + 1] = fmaf(w, hi, acc[2 * k + 1]);
    }
}

__device__ __forceinline__ void trilinear_core(float px, float py, float pz,
                                               const uint32_t* __restrict__ gt,
                                               float acc[NCH]) {
    float x0f = floorf(px), y0f = floorf(py), z0f = floorf(pz);
    float fx = px - x0f, fy = py - y0f, fz = pz - z0f;

    int x0 = min(max((int)x0f, 0), WS - 1);
    int y0 = min(max((int)y0f, 0), HS - 1);
    int z0 = min(max((int)z0f, 0), DS - 1);
    int x1 = min(x0 + 1, WS - 1);
    int y1 = min(y0 + 1, HS - 1);
    int z1 = min(z0 + 1, DS - 1);

    float wx0 = 1.0f - fx, wx1 = fx;
    float wy0 = 1.0f - fy, wy1 = fy;
    float wz0 = 1.0f - fz, wz1 = fz;

    float w000 = wz0 * wy0 * wx0, w001 = wz0 * wy0 * wx1;
    float w010 = wz0 * wy1 * wx0, w011 = wz0 * wy1 * wx1;
    float w100 = wz1 * wy0 * wx0, w101 = wz1 * wy0 * wx1;
    float w110 = wz1 * wy1 * wx0, w111 = wz1 * wy1 * wx1;

    int zo0 = z0 * HW, zo1 = z1 * HW;
    int yo0 = y0 * WS, yo1 = y1 * WS;

#pragma unroll
    for (int c = 0; c < NCH; ++c) acc[c] = 0.0f;

    {
        uint32_t a[6], b[6];
        load_cell(gt, zo0 + yo0 + x0, a);
        load_cell(gt, zo0 + yo0 + x1, b);
        acc_cell(a, w000, acc);
        acc_cell(b, w001, acc);
    }
    {
        uint32_t a[6], b[6];
        load_cell(gt, zo0 + yo1 + x0, a);
        load_cell(gt, zo0 + yo1 + x1, b);
        acc_cell(a, w010, acc);
        acc_cell(b, w011, acc);
    }
    {
        uint32_t a[6], b[6];
        load_cell(gt, zo1 + yo0 + x0, a);
        load_cell(gt, zo1 + yo0 + x1, b);
        acc_cell(a, w100, acc);
        acc_cell(b, w101, acc);
    }
    {
        uint32_t a[6], b[6];
        load_cell(gt, zo1 + yo1 + x0, a);
        load_cell(gt, zo1 + yo1 + x1, b);
        acc_cell(a, w110, acc);
        acc_cell(b, w111, acc);
    }
}

// Sorted-points sampler. DIRECT=1: write out[orig_idx] (scattered).
// DIRECT=0: write tmp[sorted_pos] (coalesced); a gather pass permutes after.
template <int DIRECT>
__global__ __launch_bounds__(256) void sample_sorted_kernel(
    const float4* __restrict__ sorted,
    const uint32_t* __restrict__ gt,
    float* __restrict__ dst, int n)
{
    // XCD-aware swizzle: give each XCD a contiguous chunk of sorted order so a
    // bucket's grid region is fetched into one XCD's L2, not all eight.
    int nwg = gridDim.x;
    int bid = blockIdx.x;
    int q = nwg >> 3, r = nwg & 7;
    int xcd = bid & 7, lot = bid >> 3;
    int swz = (xcd < r ? xcd * (q + 1) : r * (q + 1) + (xcd - r) * q) + lot;

    int i = swz * 256 + (int)threadIdx.x;
    if (i >= n) return;

    float4 s = sorted[i];

    float acc[NCH];
    trilinear_core(s.x, s.y, s.z, gt, acc);

    size_t o = DIRECT ? (size_t)__float_as_uint(s.w) * NCH : (size_t)i * NCH;
    float4* o4 = (float4*)(dst + o);
    o4[0] = make_float4(acc[0], acc[1], acc[2], acc[3]);
    o4[1] = make_float4(acc[4], acc[5], acc[6], acc[7]);
    o4[2] = make_float4(acc[8], acc[9], acc[10], acc[11]);
}

// Final permutation: coalesced inv read, random tmp READ (cheap), coalesced
// out write.
__global__ __launch_bounds__(256) void gather_out_kernel(
    const uint32_t* __restrict__ inv, const float* __restrict__ tmp,
    float* __restrict__ out, int n)
{
    int i = blockIdx.x * blockDim.x + threadIdx.x;
    if (i >= n) return;
    size_t pos = inv[i];
    const float4* t4 = (const float4*)(tmp + pos * NCH);
    float4 a = t4[0], b = t4[1], c = t4[2];
    float4* o4 = (float4*)(out + (size_t)i * NCH);
    o4[0] = a; o4[1] = b; o4[2] = c;
}

// Unsorted fallback (round-0 best).
__global__ __launch_bounds__(256) void densegrid_sample_bf16_kernel(
    const float* __restrict__ xyz,
    const uint32_t* __restrict__ gt,
    const float* __restrict__ xyz_min,
    const float* __restrict__ xyz_max,
    float* __restrict__ out,
    int n)
{
    int i = blockIdx.x * blockDim.x + threadIdx.x;
    if (i >= n) return;

    float px, py, pz;
    to_grid(xyz[3 * i + 0], xyz[3 * i + 1], xyz[3 * i + 2],
            xyz_min, xyz_max, px, py, pz);

    float acc[NCH];
    trilinear_core(px, py, pz, gt, acc);

    float4* o4 = (float4*)(out + (size_t)i * NCH);
    o4[0] = make_float4(acc[0], acc[1], acc[2], acc[3]);
    o4[1] = make_float4(acc[4], acc[5], acc[6], acc[7]);
    o4[2] = make_float4(acc[8], acc[9], acc[10], acc[11]);
}

// fp32 channel-first fallback (if workspace too small for bf16 grid).
__global__ __launch_bounds__(256) void densegrid_sample_chfirst_kernel(
    const float* __restrict__ xyz,
    const float* __restrict__ grid,
    const float* __restrict__ xyz_min,
    const float* __restrict__ xyz_max,
    float* __restrict__ out,
    int n)
{
    int i = blockIdx.x * blockDim.x + threadIdx.x;
    if (i >= n) return;

    float px, py, pz;
    to_grid(xyz[3 * i + 0], xyz[3 * i + 1], xyz[3 * i + 2],
            xyz_min, xyz_max, px, py, pz);

    float x0f = floorf(px), y0f = floorf(py), z0f = floorf(pz);
    float fx = px - x0f, fy = py - y0f, fz = pz - z0f;

    int x0 = min(max((int)x0f, 0), WS - 1);
    int y0 = min(max((int)y0f, 0), HS - 1);
    int z0 = min(max((int)z0f, 0), DS - 1);
    int x1 = min(x0 + 1, WS - 1);
    int y1 = min(y0 + 1, HS - 1);
    int z1 = min(z0 + 1, DS - 1);

    float wx0 = 1.0f - fx, wx1 = fx;
    float wy0 = 1.0f - fy, wy1 = fy;
    float wz0 = 1.0f - fz, wz1 = fz;

    float w000 = wz0 * wy0 * wx0, w001 = wz0 * wy0 * wx1;
    float w010 = wz0 * wy1 * wx0, w011 = wz0 * wy1 * wx1;
    float w100 = wz1 * wy0 * wx0, w101 = wz1 * wy0 * wx1;
    float w110 = wz1 * wy1 * wx0, w111 = wz1 * wy1 * wx1;

    int o00 = z0 * HW + y0 * WS;
    int o01 = z0 * HW + y1 * WS;
    int o10 = z1 * HW + y0 * WS;
    int o11 = z1 * HW + y1 * WS;

    float res[NCH];
#pragma unroll
    for (int c = 0; c < NCH; ++c) {
        const float* g = grid + (size_t)c * DHW;
        float acc = g[o00 + x0] * w000;
        acc = fmaf(g[o00 + x1], w001, acc);
        acc = fmaf(g[o01 + x0], w010, acc);
        acc = fmaf(g[o01 + x1], w011, acc);
        acc = fmaf(g[o10 + x0], w100, acc);
        acc = fmaf(g[o10 + x1], w101, acc);
        acc = fmaf(g[o11 + x0], w110, acc);
        acc = fmaf(g[o11 + x1], w111, acc);
        res[c] = acc;
    }
    float4* o4 = (float4*)(out + (size_t)i * NCH);
    o4[0] = make_float4(res[0], res[1], res[2], res[3]);
    o4[1] = make_float4(res[4], res[5], res[6], res[7]);
    o4[2] = make_float4(res[8], res[9], res[10], res[11]);
}

extern "C" void kernel_launch(void* const* d_in, const int* in_sizes, int n_in,
                              void* d_out, int out_size, void* d_ws, size_t ws_size,
                              hipStream_t stream) {
    const float* xyz     = (const float*)d_in[0];
    const float* grid    = (const float*)d_in[1];
    const float* xyz_min = (const float*)d_in[2];
    const float* xyz_max = (const float*)d_in[3];
    float* out = (float*)d_out;

    int n = in_sizes[0] / 3;
    int block = 256;
    int blocks = (n + block - 1) / block;

    size_t gt_bytes   = (size_t)DHW * NCH * 2;              // 98,304,000 B
    size_t total_off  = gt_bytes;                           // 125 u32
    size_t cursor_off = total_off + 512;
    size_t sorted_off = cursor_off + 512;                   // 16-aligned
    size_t inv_off    = sorted_off + (size_t)n * 16;
    size_t tmp_off    = inv_off + (size_t)n * 4;
    size_t need_direct = inv_off;                           // ~131.9 MB
    size_t need_full   = tmp_off + (size_t)n * 48;          // ~240.9 MB

    int tthreads = DHW / 4;
    int tblocks  = (tthreads + block - 1) / block;          // 4000
    int sblocks  = (n + PTS_PER_BLOCK - 1) / PTS_PER_BLOCK; // 512

    if (ws_size >= need_direct) {
        uint32_t* gt     = (uint32_t*)d_ws;
        uint32_t* total  = (uint32_t*)((char*)d_ws + total_off);
        uint32_t* cursor = (uint32_t*)((char*)d_ws + cursor_off);
        float4*   sorted = (float4*)((char*)d_ws + sorted_off);
        bool full = ws_size >= need_full;
        uint32_t* inv = full ? (uint32_t*)((char*)d_ws + inv_off) : nullptr;
        float*    tmp = full ? (float*)((char*)d_ws + tmp_off) : nullptr;

        transpose_bf16_kernel<<<tblocks, block, 0, stream>>>(grid, gt);
        zero_total_kernel<<<1, 128, 0, stream>>>(total);
        hist_kernel<<<sblocks, block, 0, stream>>>(xyz, xyz_min, xyz_max, total, n);
        scan_base_kernel<<<1, 128, 0, stream>>>(total, cursor);
        scatter_kernel<<<sblocks, block, 0, stream>>>(xyz, xyz_min, xyz_max,
                                                      cursor, sorted, inv, n);
        if (full) {
            sample_sorted_kernel<0><<<blocks, block, 0, stream>>>(sorted, gt, tmp, n);
            gather_out_kernel<<<blocks, block, 0, stream>>>(inv, tmp, out, n);
        } else {
            sample_sorted_kernel<1><<<blocks, block, 0, stream>>>(sorted, gt, out, n);
        }
    } else if (ws_size >= gt_bytes) {
        uint32_t* gt = (uint32_t*)d_ws;
        transpose_bf16_kernel<<<tblocks, block, 0, stream>>>(grid, gt);
        densegrid_sample_bf16_kernel<<<blocks, block, 0, stream>>>(
            xyz, gt, xyz_min, xyz_max, out, n);
    } else {
        densegrid_sample_chfirst_kernel<<<blocks, block, 0, stream>>>(
            xyz, grid, xyz_min, xyz_max, out, n);
    }
}